// Round 2
// baseline (617.596 us; speedup 1.0000x reference)
//
#include <hip/hip_runtime.h>
#include <hip/hip_fp16.h>
#include <hip/hip_cooperative_groups.h>
#include <stdint.h>

namespace cg = cooperative_groups;

#define F_IN  128
#define HID   16
#define F_OUT 128
#define NBK   512     // dst buckets
#define NBLK  512     // grid blocks (== NBK so csr phase maps block->bucket)
#define BCAP  4096    // per-bucket edge capacity
#define CHUNK_MAX 4096
#define EPT   16      // edges/thread in partf (E <= 512*256*16)
#define XP1   132

static_assert(NBLK == NBK, "csr phase needs block==bucket");

__device__ __forceinline__ int bucket_of(int d, int N) {
    return (int)(((long long)d * NBK) / N);
}
__device__ __forceinline__ int bucket_lo(int b, int N) {
    return (int)(((long long)b * N + NBK - 1) / NBK);
}

// ---------------- shared-memory phase overlays ----------------
struct SmemPartf {
    int lh[NBK], lofs[NBK], lcur[NBK], gbase[NBK], lnlo[NBK];
    int loff[256];
    uint32_t spairs[CHUNK_MAX];
    uint16_t sbkt[CHUNK_MAX];
};                                              // 35,840 B
struct SmemCsr { int lcnt[256], loff[256], lcur[256]; };  // 3 KB
struct SmemT1  { float sX[32 * XP1]; float sWt[HID * XP1]; }; // 25,344 B

constexpr unsigned SMEM_BYTES =
    sizeof(SmemPartf) > sizeof(SmemT1) ? sizeof(SmemPartf) : sizeof(SmemT1);

// ---------------- phase 1: partition (block-local LDS counting sort) ----------------
__device__ void phase_partf(char* smem, int blk, int t,
                            const int* __restrict__ ei, int* __restrict__ bcur,
                            uint32_t* __restrict__ pairs, int E, int N) {
    SmemPartf* sp = (SmemPartf*)smem;
    int C = (E + NBLK - 1) / NBLK;
    int e0 = blk * C;
    int e1 = e0 + C; if (e1 > E) e1 = E;
    int ecnt = e1 - e0;

    for (int i = t; i < NBK; i += 256) { sp->lh[i] = 0; sp->lnlo[i] = bucket_lo(i, N); }
    __syncthreads();

    int es[EPT], ed[EPT], eb[EPT];
#pragma unroll
    for (int k = 0; k < EPT; ++k) {
        int e = e0 + k * 256 + t;
        if (e < e1) {
            es[k] = ei[e];
            ed[k] = ei[E + e];
            eb[k] = bucket_of(ed[k], N);
            atomicAdd(&sp->lh[eb[k]], 1);
        } else eb[k] = -1;
    }
    __syncthreads();

    // exclusive scan of 512 buckets with 256 threads (2 elems/thread)
    int a0 = sp->lh[2 * t], a1 = sp->lh[2 * t + 1];
    int s2 = a0 + a1;
    sp->loff[t] = s2;
    __syncthreads();
    for (int o = 1; o < 256; o <<= 1) {
        int a = (t >= o) ? sp->loff[t - o] : 0;
        __syncthreads();
        sp->loff[t] += a;
        __syncthreads();
    }
    int excl = sp->loff[t] - s2;
    sp->lofs[2 * t]     = excl;
    sp->lofs[2 * t + 1] = excl + a0;
    sp->lcur[2 * t]     = excl;
    sp->lcur[2 * t + 1] = excl + a0;
    __syncthreads();

    // reserve global bucket space: one atomic per (block,bucket), rotated
    for (int w = 0; w < NBK; w += 256) {
        int i = (t + w + blk) & (NBK - 1);
        int h = sp->lh[i];
        sp->gbase[i] = h ? atomicAdd(&bcur[i], h) : 0;
    }

    // place packed pairs into LDS, sorted by bucket
#pragma unroll
    for (int k = 0; k < EPT; ++k) {
        if (eb[k] >= 0) {
            int b = eb[k];
            int idx = atomicAdd(&sp->lcur[b], 1);
            sp->spairs[idx] = ((uint32_t)es[k] << 10) | (uint32_t)(ed[k] - sp->lnlo[b]);
            sp->sbkt[idx]   = (uint16_t)b;
        }
    }
    __syncthreads();

    // coalesced copy-out
    for (int i = t; i < ecnt; i += 256) {
        int b = sp->sbkt[i];
        int pos = sp->gbase[b] + (i - sp->lofs[b]);
        if (pos < BCAP)
            pairs[(size_t)b * BCAP + pos] = sp->spairs[i];
    }
}

// ---------------- phase 2: per-bucket CSR build ----------------
__device__ void phase_csr(char* smem, int b, int t,
                          const uint32_t* __restrict__ pairs, const int* __restrict__ bcur,
                          int* __restrict__ row_start, int* __restrict__ cnt,
                          float* __restrict__ dinv, int* __restrict__ srcs, int N) {
    SmemCsr* sc = (SmemCsr*)smem;
    int base = b * BCAP;
    int ec = bcur[b]; if (ec > BCAP) ec = BCAP;
    int nlo = bucket_lo(b, N);
    int nhi = bucket_lo(b + 1, N); if (nhi > N) nhi = N;
    int nn = nhi - nlo;
    sc->lcnt[t] = 0;
    __syncthreads();
    for (int e = t; e < ec; e += 256)
        atomicAdd(&sc->lcnt[pairs[base + e] & 1023u], 1);
    __syncthreads();
    int v = sc->lcnt[t];
    int pv = (v + 3) & ~3;                 // pad run to multiple of 4
    sc->loff[t] = pv;
    __syncthreads();
    for (int o = 1; o < 256; o <<= 1) {
        int a = (t >= o) ? sc->loff[t - o] : 0;
        __syncthreads();
        sc->loff[t] += a;
        __syncthreads();
    }
    if (t < nn) {
        int gs = base + (sc->loff[t] - pv);
        row_start[nlo + t] = gs;
        cnt[nlo + t]       = v;
        dinv[nlo + t]      = rsqrtf((float)(v + 1));
        sc->lcur[t]        = gs;
    }
    __syncthreads();
    for (int e = t; e < ec; e += 256) {
        uint32_t p = pairs[base + e];
        int pos = atomicAdd(&sc->lcur[p & 1023u], 1);
        srcs[pos] = (int)(p >> 10);
    }
}

// ---------------- phase 3: transform1, grid-stride over 32-node vblocks ----------------
__device__ void phase_t1(char* smem, int blk, int nblk, int t,
                         const float* __restrict__ x, const float* __restrict__ W1,
                         const float* __restrict__ dinv, __half* __restrict__ g1, int n) {
    SmemT1* st = (SmemT1*)smem;
    for (int i = t; i < F_IN * HID; i += 256) {
        int k = i >> 4, f = i & 15;
        st->sWt[f * XP1 + k] = W1[i];
    }
    int nvb = (n + 31) / 32;
    int f  = t & 7;
    int nl = t >> 3;
    for (int vb = blk; vb < nvb; vb += nblk) {
        __syncthreads();               // sWt ready / protect sX reuse
        int node0 = vb * 32;
        const float4* x4 = (const float4*)(x + (size_t)node0 * F_IN);
        int nrem = n - node0;
#pragma unroll
        for (int j = 0; j < 4; ++j) {
            int idx4 = t + j * 256;
            int nl2 = idx4 >> 5;
            int kk = (idx4 & 31) * 4;
            float4 v = make_float4(0.f, 0.f, 0.f, 0.f);
            if (nl2 < nrem) v = x4[idx4];
            *(float4*)&st->sX[nl2 * XP1 + kk] = v;
        }
        __syncthreads();
        float a0 = 0.f, a1 = 0.f;
        const float* xr  = &st->sX[nl * XP1];
        const float* wr0 = &st->sWt[f * XP1];
        const float* wr1 = &st->sWt[(f + 8) * XP1];
#pragma unroll 4
        for (int k = 0; k < F_IN; k += 4) {
            float4 xv = *(const float4*)(xr + k);
            float4 w0 = *(const float4*)(wr0 + k);
            float4 w1 = *(const float4*)(wr1 + k);
            a0 += xv.x * w0.x + xv.y * w0.y + xv.z * w0.z + xv.w * w0.w;
            a1 += xv.x * w1.x + xv.y * w1.y + xv.z * w1.z + xv.w * w1.w;
        }
        int node = node0 + nl;
        if (node < n) {
            float di = dinv[node];
            g1[(size_t)node * HID + f]     = __float2half(di * a0);
            g1[(size_t)node * HID + f + 8] = __float2half(di * a1);
        }
    }
}

__device__ __forceinline__ void add_h8(float* __restrict__ acc, const __half* __restrict__ ptr) {
    uint4 u = *(const uint4*)ptr;
    const __half2* h = (const __half2*)&u;
#pragma unroll
    for (int q = 0; q < 4; ++q) {
        float2 f = __half22float2(h[q]);
        acc[2 * q]     += f.x;
        acc[2 * q + 1] += f.y;
    }
}

// ---------------- gather: one (node, half) slot; 16B loads ----------------
template<bool EP1>
__device__ __forceinline__ void gather_one(
        int tt, const __half* __restrict__ g, const int* __restrict__ srcs,
        const int* __restrict__ row_start, const int* __restrict__ cnt,
        const float* __restrict__ dinv, const float* __restrict__ b1,
        __half* __restrict__ outb, int n) {
    int node = tt >> 1;
    int p = tt & 1;
    if (node >= n) return;
    int rs  = row_start[node];
    int deg = cnt[node];
    float acc[8];
    {
        uint4 u = *(const uint4*)(g + (size_t)node * HID + p * 8);
        const __half2* h = (const __half2*)&u;
#pragma unroll
        for (int q = 0; q < 4; ++q) {
            float2 f = __half22float2(h[q]);
            acc[2 * q] = f.x; acc[2 * q + 1] = f.y;
        }
    }
    int j = 0;
    for (; j + 8 <= deg; j += 8) {
        int4 ia = *(const int4*)(srcs + rs + j);
        int4 ib = *(const int4*)(srcs + rs + j + 4);
        add_h8(acc, g + (size_t)ia.x * HID + p * 8);
        add_h8(acc, g + (size_t)ia.y * HID + p * 8);
        add_h8(acc, g + (size_t)ia.z * HID + p * 8);
        add_h8(acc, g + (size_t)ia.w * HID + p * 8);
        add_h8(acc, g + (size_t)ib.x * HID + p * 8);
        add_h8(acc, g + (size_t)ib.y * HID + p * 8);
        add_h8(acc, g + (size_t)ib.z * HID + p * 8);
        add_h8(acc, g + (size_t)ib.w * HID + p * 8);
    }
    if (j + 4 <= deg) {
        int4 ia = *(const int4*)(srcs + rs + j);
        add_h8(acc, g + (size_t)ia.x * HID + p * 8);
        add_h8(acc, g + (size_t)ia.y * HID + p * 8);
        add_h8(acc, g + (size_t)ia.z * HID + p * 8);
        add_h8(acc, g + (size_t)ia.w * HID + p * 8);
        j += 4;
    }
    for (; j < deg; ++j)
        add_h8(acc, g + (size_t)srcs[rs + j] * HID + p * 8);
    if (EP1) {
        float di = dinv[node];
#pragma unroll
        for (int i = 0; i < 8; ++i)
            acc[i] = di * fmaxf(di * acc[i] + b1[p * 8 + i], 0.0f);
    }
    uint4 o;
    __half2* oh = (__half2*)&o;
#pragma unroll
    for (int q = 0; q < 4; ++q)
        oh[q] = __floats2half2_rn(acc[2 * q], acc[2 * q + 1]);
    *(uint4*)(outb + (size_t)node * HID + p * 8) = o;
}

// ---------------- phase 6: transform2, grid-stride over 32-node vblocks ----------------
__device__ void phase_t2(int blk, int nblk, int t,
                         const __half* __restrict__ agg, const float* __restrict__ W2,
                         const float* __restrict__ b2, const float* __restrict__ dinv,
                         float* __restrict__ out, int n) {
    int d = t & 127;
    int h = t >> 7;
    float wcol[HID];
#pragma unroll
    for (int f = 0; f < HID; ++f) wcol[f] = W2[f * F_OUT + d];
    float bd = b2[d];
    int nvb = (n + 31) / 32;
    for (int vb = blk; vb < nvb; vb += nblk) {
        int node0 = vb * 32;
#pragma unroll 4
        for (int i = 0; i < 16; ++i) {
            int node = node0 + h + 2 * i;
            if (node >= n) continue;
            const uint4* av = (const uint4*)(agg + (size_t)node * HID);
            uint4 u0 = av[0], u1 = av[1];
            const __half2* h0 = (const __half2*)&u0;
            const __half2* h1 = (const __half2*)&u1;
            float s = 0.f;
#pragma unroll
            for (int q = 0; q < 4; ++q) {
                float2 f0 = __half22float2(h0[q]);
                float2 f1 = __half22float2(h1[q]);
                s += f0.x * wcol[2 * q]     + f0.y * wcol[2 * q + 1];
                s += f1.x * wcol[8 + 2 * q] + f1.y * wcol[9 + 2 * q];
            }
            out[(size_t)node * F_OUT + d] = fmaxf(dinv[node] * s + bd, 0.0f);
        }
    }
}

// ---------------- fused cooperative kernel ----------------
__global__ void __launch_bounds__(256) k_fused(
        const float* __restrict__ x, const int* __restrict__ ei,
        const float* __restrict__ W1, const float* __restrict__ b1,
        const float* __restrict__ W2, const float* __restrict__ b2,
        float* __restrict__ out,
        float* dinv, int* cnt, int* row_start, int* bcur, int* srcs,
        uint32_t* pairs, __half* bufA, __half* bufB, int N, int E) {
    extern __shared__ char smem[];
    cg::grid_group grid = cg::this_grid();
    const int t = threadIdx.x, blk = blockIdx.x;

    if (t == 0) bcur[blk] = 0;           // NBLK == NBK
    grid.sync();

    phase_partf(smem, blk, t, ei, bcur, pairs, E, N);
    grid.sync();

    phase_csr(smem, blk, t, pairs, bcur, row_start, cnt, dinv, srcs, N);
    grid.sync();

    phase_t1(smem, blk, gridDim.x, t, x, W1, dinv, bufA, N);
    grid.sync();

    {
        int gtid = blk * 256 + t, nthr = gridDim.x * 256;
        for (int tt = gtid; tt < 2 * N; tt += nthr)
            gather_one<true>(tt, bufA, srcs, row_start, cnt, dinv, b1, bufB, N);
    }
    grid.sync();
    {
        int gtid = blk * 256 + t, nthr = gridDim.x * 256;
        for (int tt = gtid; tt < 2 * N; tt += nthr)
            gather_one<false>(tt, bufB, srcs, row_start, cnt, dinv, b1, bufA, N);
    }
    grid.sync();

    phase_t2(blk, gridDim.x, t, bufA, W2, b2, dinv, out, N);
}

// ---------------- standalone fallback wrappers (no grid.sync) ----------------
__global__ void __launch_bounds__(256) k_partf_s(const int* ei, int* bcur,
                                                 uint32_t* pairs, int E, int N) {
    extern __shared__ char smem[];
    phase_partf(smem, blockIdx.x, threadIdx.x, ei, bcur, pairs, E, N);
}
__global__ void __launch_bounds__(256) k_csr_s(const uint32_t* pairs, const int* bcur,
                                               int* row_start, int* cnt, float* dinv,
                                               int* srcs, int N) {
    extern __shared__ char smem[];
    phase_csr(smem, blockIdx.x, threadIdx.x, pairs, bcur, row_start, cnt, dinv, srcs, N);
}
__global__ void __launch_bounds__(256) k_t1_s(const float* x, const float* W1,
                                              const float* dinv, __half* g1, int n) {
    extern __shared__ char smem[];
    phase_t1(smem, blockIdx.x, gridDim.x, threadIdx.x, x, W1, dinv, g1, n);
}
template<bool EP1>
__global__ void __launch_bounds__(256) k_gather_s(const __half* g, const int* srcs,
                                                  const int* row_start, const int* cnt,
                                                  const float* dinv, const float* b1,
                                                  __half* outb, int n) {
    int tt = blockIdx.x * 256 + threadIdx.x;
    if (tt < 2 * n)
        gather_one<EP1>(tt, g, srcs, row_start, cnt, dinv, b1, outb, n);
}
__global__ void __launch_bounds__(256) k_t2_s(const __half* agg, const float* W2,
                                              const float* b2, const float* dinv,
                                              float* out, int n) {
    phase_t2(blockIdx.x, gridDim.x, threadIdx.x, agg, W2, b2, dinv, out, n);
}

extern "C" void kernel_launch(void* const* d_in, const int* in_sizes, int n_in,
                              void* d_out, int out_size, void* d_ws, size_t ws_size,
                              hipStream_t stream) {
    const float* x  = (const float*)d_in[0];
    const int*   ei = (const int*)d_in[1];
    const float* W1 = (const float*)d_in[2];
    const float* b1 = (const float*)d_in[3];
    const float* W2 = (const float*)d_in[4];
    const float* b2 = (const float*)d_in[5];
    float* out = (float*)d_out;

    int N = in_sizes[0] / F_IN;
    int E = in_sizes[1] / 2;

    // workspace layout:
    float* dinv      = (float*)d_ws;                       // N
    int*   cnt       = (int*)(dinv + N);                   // N
    int*   row_start = cnt + N;                            // N
    int*   bcur      = row_start + N;                      // NBK
    int*   srcs      = bcur + NBK;                         // NBK*BCAP
    uintptr_t xb = (uintptr_t)(srcs + (size_t)NBK * BCAP + 64);
    xb = (xb + 15) & ~(uintptr_t)15;
    uint32_t* pairs = (uint32_t*)xb;                       // NBK*BCAP (build only)
    __half* bufA = (__half*)xb;                            // N*HID halves (reuses pairs)
    __half* bufB = bufA + (size_t)N * HID;                 // N*HID halves

    void* kargs[] = {
        (void*)&x, (void*)&ei, (void*)&W1, (void*)&b1, (void*)&W2, (void*)&b2,
        (void*)&out, (void*)&dinv, (void*)&cnt, (void*)&row_start, (void*)&bcur,
        (void*)&srcs, (void*)&pairs, (void*)&bufA, (void*)&bufB,
        (void*)&N, (void*)&E
    };
    hipError_t err = hipLaunchCooperativeKernel((const void*)k_fused,
                                                dim3(NBLK), dim3(256),
                                                kargs, SMEM_BYTES, stream);
    if (err != hipSuccess) {
        // fallback: original multi-dispatch pipeline
        hipMemsetAsync(bcur, 0, NBK * sizeof(int), stream);
        k_partf_s<<<NBLK, 256, sizeof(SmemPartf), stream>>>(ei, bcur, pairs, E, N);
        k_csr_s <<<NBK, 256, sizeof(SmemCsr), stream>>>(pairs, bcur, row_start, cnt, dinv, srcs, N);
        k_t1_s  <<<(N + 31) / 32, 256, sizeof(SmemT1), stream>>>(x, W1, dinv, bufA, N);
        k_gather_s<true> <<<((size_t)N * 2 + 255) / 256, 256, 0, stream>>>(
            bufA, srcs, row_start, cnt, dinv, b1, bufB, N);
        k_gather_s<false><<<((size_t)N * 2 + 255) / 256, 256, 0, stream>>>(
            bufB, srcs, row_start, cnt, dinv, b1, bufA, N);
        k_t2_s  <<<(N + 31) / 32, 256, 0, stream>>>(bufA, W2, b2, dinv, out, N);
    }
}

// Round 3
// 210.894 us; speedup vs baseline: 2.9285x; 2.9285x over previous
//
#include <hip/hip_runtime.h>
#include <hip/hip_fp16.h>
#include <stdint.h>

#define F_IN  128
#define HID   16
#define F_OUT 128
#define NBK   512     // dst buckets
#define NBLK  512     // partition blocks
#define BCAP  4096    // per-bucket edge capacity (mean 3125 + slack)
#define CHUNK_MAX 4096
#define EPT   16      // edges/thread in partf (E <= 512*256*16 = 2.09M)
#define XP1   132
#define GT2_NODES 128 // nodes per block in fused gather2+t2

__device__ __forceinline__ int bucket_of(int d, int N) {
    return (int)(((long long)d * NBK) / N);
}
__device__ __forceinline__ int bucket_lo(int b, int N) {
    return (int)(((long long)b * N + NBK - 1) / NBK);
}

// ---------- partition: block-local LDS counting sort, coalesced output ----------
__global__ void __launch_bounds__(256) k_partf(
        const int* __restrict__ ei, int* __restrict__ bcur,
        uint32_t* __restrict__ pairs, int E, int N) {
    __shared__ int lh[NBK], lofs[NBK], lcur[NBK], gbase[NBK], lnlo[NBK];
    __shared__ int loff[256];
    __shared__ uint32_t spairs[CHUNK_MAX];
    __shared__ uint16_t sbkt[CHUNK_MAX];

    int blk = blockIdx.x, t = threadIdx.x;
    int C = (E + NBLK - 1) / NBLK;
    int e0 = blk * C;
    int e1 = e0 + C; if (e1 > E) e1 = E;
    int ecnt = e1 - e0;

    for (int i = t; i < NBK; i += 256) { lh[i] = 0; lnlo[i] = bucket_lo(i, N); }
    __syncthreads();

    int es[EPT], ed[EPT], eb[EPT];
#pragma unroll
    for (int k = 0; k < EPT; ++k) {
        int e = e0 + k * 256 + t;
        if (e < e1) {
            es[k] = ei[e];
            ed[k] = ei[E + e];
            eb[k] = bucket_of(ed[k], N);
            atomicAdd(&lh[eb[k]], 1);
        } else eb[k] = -1;
    }
    __syncthreads();

    // exclusive scan of 512 buckets with 256 threads (2 elems/thread)
    int a0 = lh[2 * t], a1 = lh[2 * t + 1];
    int s2 = a0 + a1;
    loff[t] = s2;
    __syncthreads();
    for (int o = 1; o < 256; o <<= 1) {
        int a = (t >= o) ? loff[t - o] : 0;
        __syncthreads();
        loff[t] += a;
        __syncthreads();
    }
    int excl = loff[t] - s2;
    lofs[2 * t]     = excl;
    lofs[2 * t + 1] = excl + a0;
    lcur[2 * t]     = excl;
    lcur[2 * t + 1] = excl + a0;
    __syncthreads();

    // reserve global bucket space: one atomic per (block,bucket), rotated
    for (int w = 0; w < NBK; w += 256) {
        int i = (t + w + blk) & (NBK - 1);
        int h = lh[i];
        gbase[i] = h ? atomicAdd(&bcur[i], h) : 0;
    }

    // place packed pairs into LDS, sorted by bucket
#pragma unroll
    for (int k = 0; k < EPT; ++k) {
        if (eb[k] >= 0) {
            int b = eb[k];
            int idx = atomicAdd(&lcur[b], 1);
            spairs[idx] = ((uint32_t)es[k] << 10) | (uint32_t)(ed[k] - lnlo[b]);
            sbkt[idx]   = (uint16_t)b;
        }
    }
    __syncthreads();

    // coalesced copy-out: consecutive i -> consecutive global pos within a run
    for (int i = t; i < ecnt; i += 256) {
        int b = sbkt[i];
        int pos = gbase[b] + (i - lofs[b]);
        if (pos < BCAP)
            pairs[(size_t)b * BCAP + pos] = spairs[i];
    }
}

// ---------- fused: per-bucket CSR build + transform1 for the bucket's nodes ----------
// block b owns nodes [nlo, nhi) -- exactly the nodes whose dinv it computes.
__global__ void __launch_bounds__(256) k_csr_t1(
        const uint32_t* __restrict__ pairs, const int* __restrict__ bcur,
        const float* __restrict__ x, const float* __restrict__ W1,
        int* __restrict__ row_start, int* __restrict__ cnt,
        float* __restrict__ dinv, int* __restrict__ srcs,
        __half* __restrict__ g1, int N) {
    __shared__ union {
        struct { int lcnt[256]; int loff[256]; int lcur[256]; } c;
        struct { float sX[32 * XP1]; float sWt[HID * XP1]; } t1;
    } u;
    __shared__ float sdinv[224];

    int b = blockIdx.x, t = threadIdx.x;
    int base = b * BCAP;
    int ec = bcur[b]; if (ec > BCAP) ec = BCAP;
    int nlo = bucket_lo(b, N);
    int nhi = bucket_lo(b + 1, N); if (nhi > N) nhi = N;
    int nn = nhi - nlo;                    // <= 196

    // ---- CSR phase ----
    u.c.lcnt[t] = 0;
    __syncthreads();
    for (int e = t; e < ec; e += 256)
        atomicAdd(&u.c.lcnt[pairs[base + e] & 1023u], 1);
    __syncthreads();
    int v = u.c.lcnt[t];
    int pv = (v + 3) & ~3;                 // pad run to multiple of 4
    u.c.loff[t] = pv;
    __syncthreads();
    for (int o = 1; o < 256; o <<= 1) {
        int a = (t >= o) ? u.c.loff[t - o] : 0;
        __syncthreads();
        u.c.loff[t] += a;
        __syncthreads();
    }
    if (t < nn) {
        int gs = base + (u.c.loff[t] - pv);
        row_start[nlo + t] = gs;
        cnt[nlo + t]       = v;
        float dv = rsqrtf((float)(v + 1));
        dinv[nlo + t]      = dv;
        sdinv[t]           = dv;
        u.c.lcur[t]        = gs;
    }
    __syncthreads();
    for (int e = t; e < ec; e += 256) {
        uint32_t p = pairs[base + e];
        int pos = atomicAdd(&u.c.lcur[p & 1023u], 1);
        srcs[pos] = (int)(p >> 10);
    }
    __syncthreads();   // csr LDS dead; sdinv complete

    // ---- transform1 phase: g1[n] = half(dinv[n] * (x[n] @ W1)) for n in [nlo,nhi) ----
    for (int i = t; i < F_IN * HID; i += 256) {
        int k = i >> 4, f = i & 15;
        u.t1.sWt[f * XP1 + k] = W1[i];
    }
    int f  = t & 7;
    int nl = t >> 3;
    for (int c0 = 0; c0 < nn; c0 += 32) {
        __syncthreads();               // sWt ready / protect sX reuse
        int node0 = nlo + c0;
        int nrem = nn - c0;            // nodes in this chunk (clipped below 32 at tail)
        const float4* x4 = (const float4*)(x + (size_t)node0 * F_IN);
#pragma unroll
        for (int j = 0; j < 4; ++j) {
            int idx4 = t + j * 256;
            int nl2 = idx4 >> 5;
            int kk = (idx4 & 31) * 4;
            float4 vv = make_float4(0.f, 0.f, 0.f, 0.f);
            if (nl2 < nrem) vv = x4[idx4];
            *(float4*)&u.t1.sX[nl2 * XP1 + kk] = vv;
        }
        __syncthreads();
        float a0 = 0.f, a1 = 0.f;
        const float* xr  = &u.t1.sX[nl * XP1];
        const float* wr0 = &u.t1.sWt[f * XP1];
        const float* wr1 = &u.t1.sWt[(f + 8) * XP1];
#pragma unroll 4
        for (int k = 0; k < F_IN; k += 4) {
            float4 xv = *(const float4*)(xr + k);
            float4 w0 = *(const float4*)(wr0 + k);
            float4 w1 = *(const float4*)(wr1 + k);
            a0 += xv.x * w0.x + xv.y * w0.y + xv.z * w0.z + xv.w * w0.w;
            a1 += xv.x * w1.x + xv.y * w1.y + xv.z * w1.z + xv.w * w1.w;
        }
        if (nl < nrem) {
            int node = node0 + nl;
            float di = sdinv[c0 + nl];
            g1[(size_t)node * HID + f]     = __float2half(di * a0);
            g1[(size_t)node * HID + f + 8] = __float2half(di * a1);
        }
    }
}

__device__ __forceinline__ void add_h8(float* __restrict__ acc, const __half* __restrict__ ptr) {
    uint4 u = *(const uint4*)ptr;
    const __half2* h = (const __half2*)&u;
#pragma unroll
    for (int q = 0; q < 4; ++q) {
        float2 f = __half22float2(h[q]);
        acc[2 * q]     += f.x;
        acc[2 * q + 1] += f.y;
    }
}

// accumulate self + neighbors into acc[8] for (node, half p)
__device__ __forceinline__ void gather_acc(
        float* __restrict__ acc, int node, int p,
        const __half* __restrict__ g, const int* __restrict__ srcs,
        int rs, int deg) {
    {
        uint4 u = *(const uint4*)(g + (size_t)node * HID + p * 8);
        const __half2* h = (const __half2*)&u;
#pragma unroll
        for (int q = 0; q < 4; ++q) {
            float2 f = __half22float2(h[q]);
            acc[2 * q] = f.x; acc[2 * q + 1] = f.y;
        }
    }
    int j = 0;
    for (; j + 8 <= deg; j += 8) {
        int4 ia = *(const int4*)(srcs + rs + j);
        int4 ib = *(const int4*)(srcs + rs + j + 4);
        add_h8(acc, g + (size_t)ia.x * HID + p * 8);
        add_h8(acc, g + (size_t)ia.y * HID + p * 8);
        add_h8(acc, g + (size_t)ia.z * HID + p * 8);
        add_h8(acc, g + (size_t)ia.w * HID + p * 8);
        add_h8(acc, g + (size_t)ib.x * HID + p * 8);
        add_h8(acc, g + (size_t)ib.y * HID + p * 8);
        add_h8(acc, g + (size_t)ib.z * HID + p * 8);
        add_h8(acc, g + (size_t)ib.w * HID + p * 8);
    }
    if (j + 4 <= deg) {
        int4 ia = *(const int4*)(srcs + rs + j);
        add_h8(acc, g + (size_t)ia.x * HID + p * 8);
        add_h8(acc, g + (size_t)ia.y * HID + p * 8);
        add_h8(acc, g + (size_t)ia.z * HID + p * 8);
        add_h8(acc, g + (size_t)ia.w * HID + p * 8);
        j += 4;
    }
    for (; j < deg; ++j)
        add_h8(acc, g + (size_t)srcs[rs + j] * HID + p * 8);
}

// ---------- layer-1 gather: 2 threads/node, 16B loads, relu epilogue ----------
__global__ void __launch_bounds__(256) k_gather1(
        const __half* __restrict__ g, const int* __restrict__ srcs,
        const int* __restrict__ row_start, const int* __restrict__ cnt,
        const float* __restrict__ dinv, const float* __restrict__ b1,
        __half* __restrict__ outb, int n) {
    int tt = blockIdx.x * 256 + threadIdx.x;
    int node = tt >> 1;
    int p = tt & 1;
    if (node >= n) return;
    float acc[8];
    gather_acc(acc, node, p, g, srcs, row_start[node], cnt[node]);
    float di = dinv[node];
#pragma unroll
    for (int i = 0; i < 8; ++i)
        acc[i] = di * fmaxf(di * acc[i] + b1[p * 8 + i], 0.0f);
    uint4 o;
    __half2* oh = (__half2*)&o;
#pragma unroll
    for (int q = 0; q < 4; ++q)
        oh[q] = __floats2half2_rn(acc[2 * q], acc[2 * q + 1]);
    *(uint4*)(outb + (size_t)node * HID + p * 8) = o;
}

// ---------- fused layer-2 gather + transform2: agg stays in LDS ----------
__global__ void __launch_bounds__(256) k_gather_t2(
        const __half* __restrict__ g, const int* __restrict__ srcs,
        const int* __restrict__ row_start, const int* __restrict__ cnt,
        const float* __restrict__ dinv, const float* __restrict__ W2,
        const float* __restrict__ b2, float* __restrict__ out, int n) {
    __shared__ __half sAgg[GT2_NODES * HID];   // 4 KB
    __shared__ float  sdv[GT2_NODES];
    int t = threadIdx.x;
    int node0 = blockIdx.x * GT2_NODES;

    // phase A: gather 128 nodes (2 threads/node), raw sums into LDS
    {
        int nl = t >> 1, p = t & 1;
        int node = node0 + nl;
        if (node < n) {
            if (p == 0) sdv[nl] = dinv[node];
            float acc[8];
            gather_acc(acc, node, p, g, srcs, row_start[node], cnt[node]);
            uint4 o;
            __half2* oh = (__half2*)&o;
#pragma unroll
            for (int q = 0; q < 4; ++q)
                oh[q] = __floats2half2_rn(acc[2 * q], acc[2 * q + 1]);
            *(uint4*)&sAgg[nl * HID + p * 8] = o;
        }
    }
    __syncthreads();

    // phase B: out[node][d0..d0+3] = relu(dinv * (agg @ W2) + b2)
    int d0 = (t & 31) * 4;     // 32 groups x 4 dims = 128
    int h  = t >> 5;           // 8 node-subgroups
    float4 wcv[HID];
#pragma unroll
    for (int f2 = 0; f2 < HID; ++f2)
        wcv[f2] = *(const float4*)(W2 + f2 * F_OUT + d0);
    float4 bv = *(const float4*)(b2 + d0);
#pragma unroll 4
    for (int i = 0; i < GT2_NODES / 8; ++i) {
        int nl = h + 8 * i;
        int node = node0 + nl;
        if (node >= n) continue;
        const __half2* ah = (const __half2*)&sAgg[nl * HID];
        float4 s = make_float4(0.f, 0.f, 0.f, 0.f);
#pragma unroll
        for (int f2 = 0; f2 < HID; f2 += 2) {
            float2 fa = __half22float2(ah[f2 >> 1]);
            float4 w0 = wcv[f2], w1 = wcv[f2 + 1];
            s.x += fa.x * w0.x + fa.y * w1.x;
            s.y += fa.x * w0.y + fa.y * w1.y;
            s.z += fa.x * w0.z + fa.y * w1.z;
            s.w += fa.x * w0.w + fa.y * w1.w;
        }
        float dv = sdv[nl];
        float4 ov;
        ov.x = fmaxf(dv * s.x + bv.x, 0.f);
        ov.y = fmaxf(dv * s.y + bv.y, 0.f);
        ov.z = fmaxf(dv * s.z + bv.z, 0.f);
        ov.w = fmaxf(dv * s.w + bv.w, 0.f);
        *(float4*)(out + (size_t)node * F_OUT + d0) = ov;
    }
}

extern "C" void kernel_launch(void* const* d_in, const int* in_sizes, int n_in,
                              void* d_out, int out_size, void* d_ws, size_t ws_size,
                              hipStream_t stream) {
    const float* x  = (const float*)d_in[0];
    const int*   ei = (const int*)d_in[1];
    const float* W1 = (const float*)d_in[2];
    const float* b1 = (const float*)d_in[3];
    const float* W2 = (const float*)d_in[4];
    const float* b2 = (const float*)d_in[5];
    float* out = (float*)d_out;

    const int N = in_sizes[0] / F_IN;
    const int E = in_sizes[1] / 2;

    // workspace layout (all disjoint -- t1 now overlaps csr in time):
    float* dinv      = (float*)d_ws;                       // N
    int*   cnt       = (int*)(dinv + N);                   // N
    int*   row_start = cnt + N;                            // N
    int*   bcur      = row_start + N;                      // NBK
    int*   srcs      = bcur + NBK;                         // NBK*BCAP
    uint32_t* pairs  = (uint32_t*)(srcs + (size_t)NBK * BCAP);  // NBK*BCAP
    __half* bufA     = (__half*)(pairs + (size_t)NBK * BCAP);   // N*HID halves
    __half* bufB     = bufA + (size_t)N * HID;                  // N*HID halves

    hipMemsetAsync(bcur, 0, NBK * sizeof(int), stream);
    k_partf<<<NBLK, 256, 0, stream>>>(ei, bcur, pairs, E, N);
    k_csr_t1<<<NBK, 256, 0, stream>>>(pairs, bcur, x, W1,
                                      row_start, cnt, dinv, srcs, bufA, N);
    k_gather1<<<((size_t)N * 2 + 255) / 256, 256, 0, stream>>>(
        bufA, srcs, row_start, cnt, dinv, b1, bufB, N);
    k_gather_t2<<<(N + GT2_NODES - 1) / GT2_NODES, 256, 0, stream>>>(
        bufB, srcs, row_start, cnt, dinv, W2, b2, out, N);
}

// Round 4
// 201.861 us; speedup vs baseline: 3.0595x; 1.0447x over previous
//
#include <hip/hip_runtime.h>
#include <hip/hip_fp16.h>
#include <stdint.h>

#define F_IN  128
#define HID   16
#define F_OUT 128
#define NBK   512     // dst buckets
#define NBLK  512     // partition blocks
#define BCAP  4096    // per-bucket edge capacity (mean 3125 + slack)
#define CHUNK_MAX 4096
#define EPT   16      // edges/thread in partf (E <= 512*256*16 = 2.09M)
#define XP1   132
#define GT2_NODES 128 // nodes per block in fused gather2+t2

__device__ __forceinline__ int bucket_of(int d, int N) {
    return (int)(((long long)d * NBK) / N);
}
__device__ __forceinline__ int bucket_lo(int b, int N) {
    return (int)(((long long)b * N + NBK - 1) / NBK);
}

// ---------- partition: block-local LDS counting sort, coalesced output ----------
__global__ void __launch_bounds__(256) k_partf(
        const int* __restrict__ ei, int* __restrict__ bcur,
        uint32_t* __restrict__ pairs, int E, int N) {
    __shared__ int lh[NBK], lofs[NBK], lcur[NBK], gbase[NBK], lnlo[NBK];
    __shared__ int loff[256];
    __shared__ uint32_t spairs[CHUNK_MAX];
    __shared__ uint16_t sbkt[CHUNK_MAX];

    int blk = blockIdx.x, t = threadIdx.x;
    int C = (E + NBLK - 1) / NBLK;
    int e0 = blk * C;
    int e1 = e0 + C; if (e1 > E) e1 = E;
    int ecnt = e1 - e0;

    for (int i = t; i < NBK; i += 256) { lh[i] = 0; lnlo[i] = bucket_lo(i, N); }
    __syncthreads();

    int es[EPT], ed[EPT], eb[EPT];
#pragma unroll
    for (int k = 0; k < EPT; ++k) {
        int e = e0 + k * 256 + t;
        if (e < e1) {
            es[k] = ei[e];
            ed[k] = ei[E + e];
            eb[k] = bucket_of(ed[k], N);
            atomicAdd(&lh[eb[k]], 1);
        } else eb[k] = -1;
    }
    __syncthreads();

    // exclusive scan of 512 buckets with 256 threads (2 elems/thread)
    int a0 = lh[2 * t], a1 = lh[2 * t + 1];
    int s2 = a0 + a1;
    loff[t] = s2;
    __syncthreads();
    for (int o = 1; o < 256; o <<= 1) {
        int a = (t >= o) ? loff[t - o] : 0;
        __syncthreads();
        loff[t] += a;
        __syncthreads();
    }
    int excl = loff[t] - s2;
    lofs[2 * t]     = excl;
    lofs[2 * t + 1] = excl + a0;
    lcur[2 * t]     = excl;
    lcur[2 * t + 1] = excl + a0;
    __syncthreads();

    // reserve global bucket space: one atomic per (block,bucket), rotated
    for (int w = 0; w < NBK; w += 256) {
        int i = (t + w + blk) & (NBK - 1);
        int h = lh[i];
        gbase[i] = h ? atomicAdd(&bcur[i], h) : 0;
    }

    // place packed pairs into LDS, sorted by bucket
#pragma unroll
    for (int k = 0; k < EPT; ++k) {
        if (eb[k] >= 0) {
            int b = eb[k];
            int idx = atomicAdd(&lcur[b], 1);
            spairs[idx] = ((uint32_t)es[k] << 10) | (uint32_t)(ed[k] - lnlo[b]);
            sbkt[idx]   = (uint16_t)b;
        }
    }
    __syncthreads();

    // coalesced copy-out: consecutive i -> consecutive global pos within a run
    for (int i = t; i < ecnt; i += 256) {
        int b = sbkt[i];
        int pos = gbase[b] + (i - lofs[b]);
        if (pos < BCAP)
            pairs[(size_t)b * BCAP + pos] = spairs[i];
    }
}

// ---------- per-bucket CSR build; runs padded to 4 for int4 index loads ----------
__global__ void __launch_bounds__(256) k_csr2(
        const uint32_t* __restrict__ pairs, const int* __restrict__ bcur,
        int* __restrict__ row_start, int* __restrict__ cnt,
        float* __restrict__ dinv, int* __restrict__ srcs, int N) {
    __shared__ int lcnt[256];
    __shared__ int loff[256];
    __shared__ int lcur[256];
    int b = blockIdx.x, t = threadIdx.x;
    int base = b * BCAP;
    int ec = bcur[b]; if (ec > BCAP) ec = BCAP;
    int nlo = bucket_lo(b, N);
    int nhi = bucket_lo(b + 1, N); if (nhi > N) nhi = N;
    int nn = nhi - nlo;                    // <= 196
    lcnt[t] = 0;
    __syncthreads();
    for (int e = t; e < ec; e += 256)
        atomicAdd(&lcnt[pairs[base + e] & 1023u], 1);
    __syncthreads();
    int v = lcnt[t];
    int pv = (v + 3) & ~3;                 // pad run to multiple of 4
    loff[t] = pv;
    __syncthreads();
    for (int o = 1; o < 256; o <<= 1) {
        int a = (t >= o) ? loff[t - o] : 0;
        __syncthreads();
        loff[t] += a;
        __syncthreads();
    }
    if (t < nn) {
        int gs = base + (loff[t] - pv);    // exclusive, 4-aligned
        row_start[nlo + t] = gs;
        cnt[nlo + t]       = v;
        dinv[nlo + t]      = rsqrtf((float)(v + 1));
        lcur[t]            = gs;
    }
    __syncthreads();
    for (int e = t; e < ec; e += 256) {
        uint32_t p = pairs[base + e];
        int pos = atomicAdd(&lcur[p & 1023u], 1);
        srcs[pos] = (int)(p >> 10);
    }
}

// ---------- layer 1 transform: g1 = half(dinv * (x @ W1)) ----------
__global__ void __launch_bounds__(256) k_transform1(
        const float* __restrict__ x, const float* __restrict__ W1,
        const float* __restrict__ dinv, __half* __restrict__ g1, int n) {
    __shared__ float sX[32 * XP1];
    __shared__ float sWt[HID * XP1];
    int t = threadIdx.x;
    int node0 = blockIdx.x * 32;
    for (int i = t; i < F_IN * HID; i += 256) {
        int k = i >> 4, f = i & 15;
        sWt[f * XP1 + k] = W1[i];
    }
    const float4* x4 = (const float4*)(x + (size_t)node0 * F_IN);
    int nrem = n - node0;
#pragma unroll
    for (int j = 0; j < 4; ++j) {
        int idx4 = t + j * 256;
        int nl = idx4 >> 5;
        int kk = (idx4 & 31) * 4;
        float4 v = make_float4(0.f, 0.f, 0.f, 0.f);
        if (nl < nrem) v = x4[idx4];
        *(float4*)&sX[nl * XP1 + kk] = v;
    }
    __syncthreads();
    int f  = t & 7;
    int nl = t >> 3;
    float a0 = 0.f, a1 = 0.f;
    const float* xr  = &sX[nl * XP1];
    const float* wr0 = &sWt[f * XP1];
    const float* wr1 = &sWt[(f + 8) * XP1];
#pragma unroll 4
    for (int k = 0; k < F_IN; k += 4) {
        float4 xv = *(const float4*)(xr + k);
        float4 w0 = *(const float4*)(wr0 + k);
        float4 w1 = *(const float4*)(wr1 + k);
        a0 += xv.x * w0.x + xv.y * w0.y + xv.z * w0.z + xv.w * w0.w;
        a1 += xv.x * w1.x + xv.y * w1.y + xv.z * w1.z + xv.w * w1.w;
    }
    int node = node0 + nl;
    if (node < n) {
        float di = dinv[node];
        g1[(size_t)node * HID + f]     = __float2half(di * a0);
        g1[(size_t)node * HID + f + 8] = __float2half(di * a1);
    }
}

__device__ __forceinline__ void add_h8(float* __restrict__ acc, const __half* __restrict__ ptr) {
    uint4 u = *(const uint4*)ptr;
    const __half2* h = (const __half2*)&u;
#pragma unroll
    for (int q = 0; q < 4; ++q) {
        float2 f = __half22float2(h[q]);
        acc[2 * q]     += f.x;
        acc[2 * q + 1] += f.y;
    }
}

// accumulate self + neighbors into acc[8] for (node, half p)
__device__ __forceinline__ void gather_acc(
        float* __restrict__ acc, int node, int p,
        const __half* __restrict__ g, const int* __restrict__ srcs,
        int rs, int deg) {
    {
        uint4 u = *(const uint4*)(g + (size_t)node * HID + p * 8);
        const __half2* h = (const __half2*)&u;
#pragma unroll
        for (int q = 0; q < 4; ++q) {
            float2 f = __half22float2(h[q]);
            acc[2 * q] = f.x; acc[2 * q + 1] = f.y;
        }
    }
    int j = 0;
    for (; j + 8 <= deg; j += 8) {
        int4 ia = *(const int4*)(srcs + rs + j);
        int4 ib = *(const int4*)(srcs + rs + j + 4);
        add_h8(acc, g + (size_t)ia.x * HID + p * 8);
        add_h8(acc, g + (size_t)ia.y * HID + p * 8);
        add_h8(acc, g + (size_t)ia.z * HID + p * 8);
        add_h8(acc, g + (size_t)ia.w * HID + p * 8);
        add_h8(acc, g + (size_t)ib.x * HID + p * 8);
        add_h8(acc, g + (size_t)ib.y * HID + p * 8);
        add_h8(acc, g + (size_t)ib.z * HID + p * 8);
        add_h8(acc, g + (size_t)ib.w * HID + p * 8);
    }
    if (j + 4 <= deg) {
        int4 ia = *(const int4*)(srcs + rs + j);
        add_h8(acc, g + (size_t)ia.x * HID + p * 8);
        add_h8(acc, g + (size_t)ia.y * HID + p * 8);
        add_h8(acc, g + (size_t)ia.z * HID + p * 8);
        add_h8(acc, g + (size_t)ia.w * HID + p * 8);
        j += 4;
    }
    for (; j < deg; ++j)
        add_h8(acc, g + (size_t)srcs[rs + j] * HID + p * 8);
}

// ---------- layer-1 gather: 2 threads/node, 16B loads, relu epilogue ----------
__global__ void __launch_bounds__(256) k_gather1(
        const __half* __restrict__ g, const int* __restrict__ srcs,
        const int* __restrict__ row_start, const int* __restrict__ cnt,
        const float* __restrict__ dinv, const float* __restrict__ b1,
        __half* __restrict__ outb, int n) {
    int tt = blockIdx.x * 256 + threadIdx.x;
    int node = tt >> 1;
    int p = tt & 1;
    if (node >= n) return;
    float acc[8];
    gather_acc(acc, node, p, g, srcs, row_start[node], cnt[node]);
    float di = dinv[node];
#pragma unroll
    for (int i = 0; i < 8; ++i)
        acc[i] = di * fmaxf(di * acc[i] + b1[p * 8 + i], 0.0f);
    uint4 o;
    __half2* oh = (__half2*)&o;
#pragma unroll
    for (int q = 0; q < 4; ++q)
        oh[q] = __floats2half2_rn(acc[2 * q], acc[2 * q + 1]);
    *(uint4*)(outb + (size_t)node * HID + p * 8) = o;
}

// ---------- fused layer-2 gather + transform2: agg stays in LDS ----------
__global__ void __launch_bounds__(256) k_gather_t2(
        const __half* __restrict__ g, const int* __restrict__ srcs,
        const int* __restrict__ row_start, const int* __restrict__ cnt,
        const float* __restrict__ dinv, const float* __restrict__ W2,
        const float* __restrict__ b2, float* __restrict__ out, int n) {
    __shared__ __half sAgg[GT2_NODES * HID];   // 4 KB
    __shared__ float  sdv[GT2_NODES];
    int t = threadIdx.x;
    int node0 = blockIdx.x * GT2_NODES;

    // phase A: gather 128 nodes (2 threads/node), raw sums into LDS
    {
        int nl = t >> 1, p = t & 1;
        int node = node0 + nl;
        if (node < n) {
            if (p == 0) sdv[nl] = dinv[node];
            float acc[8];
            gather_acc(acc, node, p, g, srcs, row_start[node], cnt[node]);
            uint4 o;
            __half2* oh = (__half2*)&o;
#pragma unroll
            for (int q = 0; q < 4; ++q)
                oh[q] = __floats2half2_rn(acc[2 * q], acc[2 * q + 1]);
            *(uint4*)&sAgg[nl * HID + p * 8] = o;
        }
    }
    __syncthreads();

    // phase B: out[node][d0..d0+3] = relu(dinv * (agg @ W2) + b2)
    int d0 = (t & 31) * 4;     // 32 groups x 4 dims = 128
    int h  = t >> 5;           // 8 node-subgroups
    float4 wcv[HID];
#pragma unroll
    for (int f2 = 0; f2 < HID; ++f2)
        wcv[f2] = *(const float4*)(W2 + f2 * F_OUT + d0);
    float4 bv = *(const float4*)(b2 + d0);
#pragma unroll 4
    for (int i = 0; i < GT2_NODES / 8; ++i) {
        int nl = h + 8 * i;
        int node = node0 + nl;
        if (node >= n) continue;
        const __half2* ah = (const __half2*)&sAgg[nl * HID];
        float4 s = make_float4(0.f, 0.f, 0.f, 0.f);
#pragma unroll
        for (int f2 = 0; f2 < HID; f2 += 2) {
            float2 fa = __half22float2(ah[f2 >> 1]);
            float4 w0 = wcv[f2], w1 = wcv[f2 + 1];
            s.x += fa.x * w0.x + fa.y * w1.x;
            s.y += fa.x * w0.y + fa.y * w1.y;
            s.z += fa.x * w0.z + fa.y * w1.z;
            s.w += fa.x * w0.w + fa.y * w1.w;
        }
        float dv = sdv[nl];
        float4 ov;
        ov.x = fmaxf(dv * s.x + bv.x, 0.f);
        ov.y = fmaxf(dv * s.y + bv.y, 0.f);
        ov.z = fmaxf(dv * s.z + bv.z, 0.f);
        ov.w = fmaxf(dv * s.w + bv.w, 0.f);
        *(float4*)(out + (size_t)node * F_OUT + d0) = ov;
    }
}

extern "C" void kernel_launch(void* const* d_in, const int* in_sizes, int n_in,
                              void* d_out, int out_size, void* d_ws, size_t ws_size,
                              hipStream_t stream) {
    const float* x  = (const float*)d_in[0];
    const int*   ei = (const int*)d_in[1];
    const float* W1 = (const float*)d_in[2];
    const float* b1 = (const float*)d_in[3];
    const float* W2 = (const float*)d_in[4];
    const float* b2 = (const float*)d_in[5];
    float* out = (float*)d_out;

    const int N = in_sizes[0] / F_IN;
    const int E = in_sizes[1] / 2;

    // workspace layout (all disjoint):
    float* dinv      = (float*)d_ws;                       // N
    int*   cnt       = (int*)(dinv + N);                   // N
    int*   row_start = cnt + N;                            // N
    int*   bcur      = row_start + N;                      // NBK
    int*   srcs      = bcur + NBK;                         // NBK*BCAP
    uint32_t* pairs  = (uint32_t*)(srcs + (size_t)NBK * BCAP);  // NBK*BCAP
    __half* bufA     = (__half*)(pairs + (size_t)NBK * BCAP);   // N*HID halves
    __half* bufB     = bufA + (size_t)N * HID;                  // N*HID halves

    hipMemsetAsync(bcur, 0, NBK * sizeof(int), stream);
    k_partf<<<NBLK, 256, 0, stream>>>(ei, bcur, pairs, E, N);
    k_csr2 <<<NBK, 256, 0, stream>>>(pairs, bcur, row_start, cnt, dinv, srcs, N);
    k_transform1<<<(N + 31) / 32, 256, 0, stream>>>(x, W1, dinv, bufA, N);
    k_gather1<<<((size_t)N * 2 + 255) / 256, 256, 0, stream>>>(
        bufA, srcs, row_start, cnt, dinv, b1, bufB, N);
    k_gather_t2<<<(N + GT2_NODES - 1) / GT2_NODES, 256, 0, stream>>>(
        bufB, srcs, row_start, cnt, dinv, W2, b2, out, N);
}

// Round 5
// 198.480 us; speedup vs baseline: 3.1116x; 1.0170x over previous
//
#include <hip/hip_runtime.h>
#include <hip/hip_fp16.h>
#include <stdint.h>

#define F_IN  128
#define HID   16
#define F_OUT 128
#define NBK   512     // dst buckets
#define NBLK  512     // partition blocks
#define BCAP  4096    // per-bucket edge capacity (mean 3125 + slack)
#define CHUNK_MAX 4096
#define XP1   132
#define GT2_NODES 128 // nodes per block in fused gather2+t2

__device__ __forceinline__ int bucket_of(int d, int N) {
    return (int)(((long long)d * NBK) / N);
}
__device__ __forceinline__ int bucket_lo(int b, int N) {
    return (int)(((long long)b * N + NBK - 1) / NBK);
}

// ---------- partition: block-local LDS counting sort, int4 edge loads ----------
__global__ void __launch_bounds__(256) k_partf(
        const int* __restrict__ ei, int* __restrict__ bcur,
        uint32_t* __restrict__ pairs, int E, int N) {
    __shared__ int lh[NBK], lofs[NBK], lcur[NBK], gbase[NBK], lnlo[NBK];
    __shared__ int loff[256];
    __shared__ uint32_t spairs[CHUNK_MAX];
    __shared__ uint16_t sbkt[CHUNK_MAX];

    int blk = blockIdx.x, t = threadIdx.x;
    int Cr = (E + NBLK - 1) / NBLK;
    int C  = (Cr + 15) & ~15;            // 16-aligned chunk => 16B-aligned int4 loads
    int e0 = blk * C; if (e0 > E) e0 = E;
    int e1 = e0 + C;  if (e1 > E) e1 = E;
    int ecnt = e1 - e0;

    for (int i = t; i < NBK; i += 256) { lh[i] = 0; lnlo[i] = bucket_lo(i, N); }
    __syncthreads();

    // stage 16 edges/thread via 4x int4 (vector path valid only if E%4==0 for the dst half)
    int4 es4[4], ed4[4];
    bool evec = ((E & 3) == 0);
#pragma unroll
    for (int j = 0; j < 4; ++j) {
        int e = e0 + (j * 256 + t) * 4;
        if (evec && e + 4 <= e1) {
            es4[j] = *(const int4*)(ei + e);
            ed4[j] = *(const int4*)(ei + E + e);
        } else {
            int* s = (int*)&es4[j];
            int* d = (int*)&ed4[j];
#pragma unroll
            for (int q = 0; q < 4; ++q) {
                int ee = e + q;
                bool ok = (ee < e1);
                s[q] = ok ? ei[ee] : -1;
                d[q] = ok ? ei[E + ee] : 0;
            }
        }
    }
    const int* esv = (const int*)es4;
    const int* edv = (const int*)ed4;
    int eb[16];
#pragma unroll
    for (int k = 0; k < 16; ++k) {
        if (esv[k] >= 0) {
            eb[k] = bucket_of(edv[k], N);
            atomicAdd(&lh[eb[k]], 1);
        } else eb[k] = -1;
    }
    __syncthreads();

    // exclusive scan of 512 buckets with 256 threads (2 elems/thread)
    int a0 = lh[2 * t], a1 = lh[2 * t + 1];
    int s2 = a0 + a1;
    loff[t] = s2;
    __syncthreads();
    for (int o = 1; o < 256; o <<= 1) {
        int a = (t >= o) ? loff[t - o] : 0;
        __syncthreads();
        loff[t] += a;
        __syncthreads();
    }
    int excl = loff[t] - s2;
    lofs[2 * t]     = excl;
    lofs[2 * t + 1] = excl + a0;
    lcur[2 * t]     = excl;
    lcur[2 * t + 1] = excl + a0;
    __syncthreads();

    // reserve global bucket space: one atomic per (block,bucket), rotated
    for (int w = 0; w < NBK; w += 256) {
        int i = (t + w + blk) & (NBK - 1);
        int h = lh[i];
        gbase[i] = h ? atomicAdd(&bcur[i], h) : 0;
    }

    // place packed pairs into LDS, sorted by bucket
#pragma unroll
    for (int k = 0; k < 16; ++k) {
        if (eb[k] >= 0) {
            int b = eb[k];
            int idx = atomicAdd(&lcur[b], 1);
            spairs[idx] = ((uint32_t)esv[k] << 10) | (uint32_t)(edv[k] - lnlo[b]);
            sbkt[idx]   = (uint16_t)b;
        }
    }
    __syncthreads();

    // coalesced copy-out: consecutive i -> consecutive global pos within a run
    for (int i = t; i < ecnt; i += 256) {
        int b = sbkt[i];
        int pos = gbase[b] + (i - lofs[b]);
        if (pos < BCAP)
            pairs[(size_t)b * BCAP + pos] = spairs[i];
    }
}

// ---------- per-bucket CSR build; pairs staged in LDS, single global read ----------
__global__ void __launch_bounds__(256) k_csr2(
        const uint32_t* __restrict__ pairs, const int* __restrict__ bcur,
        int2* __restrict__ meta, float* __restrict__ dinv,
        int* __restrict__ srcs, int N) {
    __shared__ uint32_t sp[BCAP];          // 16 KB bucket staging
    __shared__ int lcnt[256];
    __shared__ int loff[256];
    __shared__ int lcur[256];
    int b = blockIdx.x, t = threadIdx.x;
    int base = b * BCAP;
    int ec = bcur[b]; if (ec > BCAP) ec = BCAP;
    int nlo = bucket_lo(b, N);
    int nhi = bucket_lo(b + 1, N); if (nhi > N) nhi = N;
    int nn = nhi - nlo;                    // <= 196
    lcnt[t] = 0;
    __syncthreads();
    // stage + histogram in one pass (uint4 loads; region is BCAP-padded so over-read is safe)
    int ec4 = (ec + 3) >> 2;
    for (int i = t; i < ec4; i += 256) {
        uint4 v = *(const uint4*)(pairs + base + i * 4);
        *(uint4*)&sp[i * 4] = v;
        int lim = ec - i * 4;
        if (lim > 0) atomicAdd(&lcnt[v.x & 1023u], 1);
        if (lim > 1) atomicAdd(&lcnt[v.y & 1023u], 1);
        if (lim > 2) atomicAdd(&lcnt[v.z & 1023u], 1);
        if (lim > 3) atomicAdd(&lcnt[v.w & 1023u], 1);
    }
    __syncthreads();
    int v = lcnt[t];
    int pv = (v + 3) & ~3;                 // pad run to multiple of 4
    loff[t] = pv;
    __syncthreads();
    for (int o = 1; o < 256; o <<= 1) {
        int a = (t >= o) ? loff[t - o] : 0;
        __syncthreads();
        loff[t] += a;
        __syncthreads();
    }
    if (t < nn) {
        int gs = base + (loff[t] - pv);    // exclusive, 4-aligned
        meta[nlo + t] = make_int2(gs, v);
        dinv[nlo + t] = rsqrtf((float)(v + 1));
        lcur[t]       = gs;
    }
    __syncthreads();
    for (int e = t; e < ec; e += 256) {
        uint32_t p = sp[e];
        int pos = atomicAdd(&lcur[p & 1023u], 1);
        srcs[pos] = (int)(p >> 10);
    }
}

// ---------- layer 1 transform: g1 = half(dinv * (x @ W1)) ----------
__global__ void __launch_bounds__(256) k_transform1(
        const float* __restrict__ x, const float* __restrict__ W1,
        const float* __restrict__ dinv, __half* __restrict__ g1, int n) {
    __shared__ float sX[32 * XP1];
    __shared__ float sWt[HID * XP1];
    int t = threadIdx.x;
    int node0 = blockIdx.x * 32;
    for (int i = t; i < F_IN * HID; i += 256) {
        int k = i >> 4, f = i & 15;
        sWt[f * XP1 + k] = W1[i];
    }
    const float4* x4 = (const float4*)(x + (size_t)node0 * F_IN);
    int nrem = n - node0;
#pragma unroll
    for (int j = 0; j < 4; ++j) {
        int idx4 = t + j * 256;
        int nl = idx4 >> 5;
        int kk = (idx4 & 31) * 4;
        float4 v = make_float4(0.f, 0.f, 0.f, 0.f);
        if (nl < nrem) v = x4[idx4];
        *(float4*)&sX[nl * XP1 + kk] = v;
    }
    __syncthreads();
    int f  = t & 7;
    int nl = t >> 3;
    float a0 = 0.f, a1 = 0.f;
    const float* xr  = &sX[nl * XP1];
    const float* wr0 = &sWt[f * XP1];
    const float* wr1 = &sWt[(f + 8) * XP1];
#pragma unroll 4
    for (int k = 0; k < F_IN; k += 4) {
        float4 xv = *(const float4*)(xr + k);
        float4 w0 = *(const float4*)(wr0 + k);
        float4 w1 = *(const float4*)(wr1 + k);
        a0 += xv.x * w0.x + xv.y * w0.y + xv.z * w0.z + xv.w * w0.w;
        a1 += xv.x * w1.x + xv.y * w1.y + xv.z * w1.z + xv.w * w1.w;
    }
    int node = node0 + nl;
    if (node < n) {
        float di = dinv[node];
        g1[(size_t)node * HID + f]     = __float2half(di * a0);
        g1[(size_t)node * HID + f + 8] = __float2half(di * a1);
    }
}

__device__ __forceinline__ void add_h8(float* __restrict__ acc, const __half* __restrict__ ptr) {
    uint4 u = *(const uint4*)ptr;
    const __half2* h = (const __half2*)&u;
#pragma unroll
    for (int q = 0; q < 4; ++q) {
        float2 f = __half22float2(h[q]);
        acc[2 * q]     += f.x;
        acc[2 * q + 1] += f.y;
    }
}

// accumulate self + neighbors into acc[8] for (node, half p)
__device__ __forceinline__ void gather_acc(
        float* __restrict__ acc, int node, int p,
        const __half* __restrict__ g, const int* __restrict__ srcs,
        int rs, int deg) {
    {
        uint4 u = *(const uint4*)(g + (size_t)node * HID + p * 8);
        const __half2* h = (const __half2*)&u;
#pragma unroll
        for (int q = 0; q < 4; ++q) {
            float2 f = __half22float2(h[q]);
            acc[2 * q] = f.x; acc[2 * q + 1] = f.y;
        }
    }
    int j = 0;
    for (; j + 8 <= deg; j += 8) {
        int4 ia = *(const int4*)(srcs + rs + j);
        int4 ib = *(const int4*)(srcs + rs + j + 4);
        add_h8(acc, g + (size_t)ia.x * HID + p * 8);
        add_h8(acc, g + (size_t)ia.y * HID + p * 8);
        add_h8(acc, g + (size_t)ia.z * HID + p * 8);
        add_h8(acc, g + (size_t)ia.w * HID + p * 8);
        add_h8(acc, g + (size_t)ib.x * HID + p * 8);
        add_h8(acc, g + (size_t)ib.y * HID + p * 8);
        add_h8(acc, g + (size_t)ib.z * HID + p * 8);
        add_h8(acc, g + (size_t)ib.w * HID + p * 8);
    }
    if (j + 4 <= deg) {
        int4 ia = *(const int4*)(srcs + rs + j);
        add_h8(acc, g + (size_t)ia.x * HID + p * 8);
        add_h8(acc, g + (size_t)ia.y * HID + p * 8);
        add_h8(acc, g + (size_t)ia.z * HID + p * 8);
        add_h8(acc, g + (size_t)ia.w * HID + p * 8);
        j += 4;
    }
    for (; j < deg; ++j)
        add_h8(acc, g + (size_t)srcs[rs + j] * HID + p * 8);
}

// ---------- layer-1 gather: 2 threads/node, 16B loads, relu epilogue ----------
__global__ void __launch_bounds__(256) k_gather1(
        const __half* __restrict__ g, const int* __restrict__ srcs,
        const int2* __restrict__ meta, const float* __restrict__ dinv,
        const float* __restrict__ b1, __half* __restrict__ outb, int n) {
    int tt = blockIdx.x * 256 + threadIdx.x;
    int node = tt >> 1;
    int p = tt & 1;
    if (node >= n) return;
    int2 m = meta[node];
    float acc[8];
    gather_acc(acc, node, p, g, srcs, m.x, m.y);
    float di = dinv[node];
#pragma unroll
    for (int i = 0; i < 8; ++i)
        acc[i] = di * fmaxf(di * acc[i] + b1[p * 8 + i], 0.0f);
    uint4 o;
    __half2* oh = (__half2*)&o;
#pragma unroll
    for (int q = 0; q < 4; ++q)
        oh[q] = __floats2half2_rn(acc[2 * q], acc[2 * q + 1]);
    *(uint4*)(outb + (size_t)node * HID + p * 8) = o;
}

// ---------- fused layer-2 gather + transform2: agg stays in LDS ----------
__global__ void __launch_bounds__(256) k_gather_t2(
        const __half* __restrict__ g, const int* __restrict__ srcs,
        const int2* __restrict__ meta, const float* __restrict__ dinv,
        const float* __restrict__ W2, const float* __restrict__ b2,
        float* __restrict__ out, int n) {
    __shared__ __half sAgg[GT2_NODES * HID];   // 4 KB
    __shared__ float  sdv[GT2_NODES];
    int t = threadIdx.x;
    int node0 = blockIdx.x * GT2_NODES;

    // phase A: gather 128 nodes (2 threads/node), raw sums into LDS
    {
        int nl = t >> 1, p = t & 1;
        int node = node0 + nl;
        if (node < n) {
            if (p == 0) sdv[nl] = dinv[node];
            int2 m = meta[node];
            float acc[8];
            gather_acc(acc, node, p, g, srcs, m.x, m.y);
            uint4 o;
            __half2* oh = (__half2*)&o;
#pragma unroll
            for (int q = 0; q < 4; ++q)
                oh[q] = __floats2half2_rn(acc[2 * q], acc[2 * q + 1]);
            *(uint4*)&sAgg[nl * HID + p * 8] = o;
        }
    }
    __syncthreads();

    // phase B: out[node][d0..d0+3] = relu(dinv * (agg @ W2) + b2)
    int d0 = (t & 31) * 4;     // 32 groups x 4 dims = 128
    int h  = t >> 5;           // 8 node-subgroups
    float4 wcv[HID];
#pragma unroll
    for (int f2 = 0; f2 < HID; ++f2)
        wcv[f2] = *(const float4*)(W2 + f2 * F_OUT + d0);
    float4 bv = *(const float4*)(b2 + d0);
#pragma unroll 4
    for (int i = 0; i < GT2_NODES / 8; ++i) {
        int nl = h + 8 * i;
        int node = node0 + nl;
        if (node >= n) continue;
        const __half2* ah = (const __half2*)&sAgg[nl * HID];
        float4 s = make_float4(0.f, 0.f, 0.f, 0.f);
#pragma unroll
        for (int f2 = 0; f2 < HID; f2 += 2) {
            float2 fa = __half22float2(ah[f2 >> 1]);
            float4 w0 = wcv[f2], w1 = wcv[f2 + 1];
            s.x += fa.x * w0.x + fa.y * w1.x;
            s.y += fa.x * w0.y + fa.y * w1.y;
            s.z += fa.x * w0.z + fa.y * w1.z;
            s.w += fa.x * w0.w + fa.y * w1.w;
        }
        float dv = sdv[nl];
        float4 ov;
        ov.x = fmaxf(dv * s.x + bv.x, 0.f);
        ov.y = fmaxf(dv * s.y + bv.y, 0.f);
        ov.z = fmaxf(dv * s.z + bv.z, 0.f);
        ov.w = fmaxf(dv * s.w + bv.w, 0.f);
        *(float4*)(out + (size_t)node * F_OUT + d0) = ov;
    }
}

extern "C" void kernel_launch(void* const* d_in, const int* in_sizes, int n_in,
                              void* d_out, int out_size, void* d_ws, size_t ws_size,
                              hipStream_t stream) {
    const float* x  = (const float*)d_in[0];
    const int*   ei = (const int*)d_in[1];
    const float* W1 = (const float*)d_in[2];
    const float* b1 = (const float*)d_in[3];
    const float* W2 = (const float*)d_in[4];
    const float* b2 = (const float*)d_in[5];
    float* out = (float*)d_out;

    const int N = in_sizes[0] / F_IN;
    const int E = in_sizes[1] / 2;

    // workspace layout (all disjoint):
    float* dinv      = (float*)d_ws;                       // N
    int2*  meta      = (int2*)(dinv + N);                  // N int2 (rs,deg) -- 16B-aligned base
    int*   bcur      = (int*)(meta + N);                   // NBK
    int*   srcs      = bcur + NBK;                         // NBK*BCAP
    uint32_t* pairs  = (uint32_t*)(srcs + (size_t)NBK * BCAP);  // NBK*BCAP
    __half* bufA     = (__half*)(pairs + (size_t)NBK * BCAP);   // N*HID halves
    __half* bufB     = bufA + (size_t)N * HID;                  // N*HID halves

    hipMemsetAsync(bcur, 0, NBK * sizeof(int), stream);
    k_partf<<<NBLK, 256, 0, stream>>>(ei, bcur, pairs, E, N);
    k_csr2 <<<NBK, 256, 0, stream>>>(pairs, bcur, meta, dinv, srcs, N);
    k_transform1<<<(N + 31) / 32, 256, 0, stream>>>(x, W1, dinv, bufA, N);
    k_gather1<<<((size_t)N * 2 + 255) / 256, 256, 0, stream>>>(
        bufA, srcs, meta, dinv, b1, bufB, N);
    k_gather_t2<<<(N + GT2_NODES - 1) / GT2_NODES, 256, 0, stream>>>(
        bufB, srcs, meta, dinv, W2, b2, out, N);
}

// Round 6
// 196.876 us; speedup vs baseline: 3.1370x; 1.0081x over previous
//
#include <hip/hip_runtime.h>
#include <hip/hip_fp16.h>
#include <stdint.h>

#define F_IN  128
#define HID   16
#define F_OUT 128
#define NBK   512     // dst buckets
#define NBLK  512     // partition blocks
#define BCAP  4096    // per-bucket edge capacity (mean 3125 + slack)
#define CHUNK_MAX 4096
#define GT2_NODES 128 // nodes per block in fused gather2+t2
#define T1N   64      // nodes per block in transform1
#define AGP   24      // sAgg padded row stride (halves)

typedef _Float16 f16;
typedef f16 f16x4 __attribute__((ext_vector_type(4)));
typedef f16 f16x8 __attribute__((ext_vector_type(8)));
typedef float f32x4 __attribute__((ext_vector_type(4)));

__device__ __forceinline__ int bucket_of(int d, int N) {
    return (int)(((long long)d * NBK) / N);
}
__device__ __forceinline__ int bucket_lo(int b, int N) {
    return (int)(((long long)b * N + NBK - 1) / NBK);
}

// ---------- partition: block-local LDS counting sort, int4 edge loads ----------
__global__ void __launch_bounds__(256) k_partf(
        const int* __restrict__ ei, int* __restrict__ bcur,
        uint32_t* __restrict__ pairs, int E, int N) {
    __shared__ int lh[NBK], lofs[NBK], lcur[NBK], gbase[NBK], lnlo[NBK];
    __shared__ int loff[256];
    __shared__ uint32_t spairs[CHUNK_MAX];
    __shared__ uint16_t sbkt[CHUNK_MAX];

    int blk = blockIdx.x, t = threadIdx.x;
    int Cr = (E + NBLK - 1) / NBLK;
    int C  = (Cr + 15) & ~15;            // 16-aligned chunk => 16B-aligned int4 loads
    int e0 = blk * C; if (e0 > E) e0 = E;
    int e1 = e0 + C;  if (e1 > E) e1 = E;
    int ecnt = e1 - e0;

    for (int i = t; i < NBK; i += 256) { lh[i] = 0; lnlo[i] = bucket_lo(i, N); }
    __syncthreads();

    int4 es4[4], ed4[4];
    bool evec = ((E & 3) == 0);
#pragma unroll
    for (int j = 0; j < 4; ++j) {
        int e = e0 + (j * 256 + t) * 4;
        if (evec && e + 4 <= e1) {
            es4[j] = *(const int4*)(ei + e);
            ed4[j] = *(const int4*)(ei + E + e);
        } else {
            int* s = (int*)&es4[j];
            int* d = (int*)&ed4[j];
#pragma unroll
            for (int q = 0; q < 4; ++q) {
                int ee = e + q;
                bool ok = (ee < e1);
                s[q] = ok ? ei[ee] : -1;
                d[q] = ok ? ei[E + ee] : 0;
            }
        }
    }
    const int* esv = (const int*)es4;
    const int* edv = (const int*)ed4;
    int eb[16];
#pragma unroll
    for (int k = 0; k < 16; ++k) {
        if (esv[k] >= 0) {
            eb[k] = bucket_of(edv[k], N);
            atomicAdd(&lh[eb[k]], 1);
        } else eb[k] = -1;
    }
    __syncthreads();

    // exclusive scan of 512 buckets with 256 threads (2 elems/thread)
    int a0 = lh[2 * t], a1 = lh[2 * t + 1];
    int s2 = a0 + a1;
    loff[t] = s2;
    __syncthreads();
    for (int o = 1; o < 256; o <<= 1) {
        int a = (t >= o) ? loff[t - o] : 0;
        __syncthreads();
        loff[t] += a;
        __syncthreads();
    }
    int excl = loff[t] - s2;
    lofs[2 * t]     = excl;
    lofs[2 * t + 1] = excl + a0;
    lcur[2 * t]     = excl;
    lcur[2 * t + 1] = excl + a0;
    __syncthreads();

    // reserve global bucket space: one atomic per (block,bucket), rotated
    for (int w = 0; w < NBK; w += 256) {
        int i = (t + w + blk) & (NBK - 1);
        int h = lh[i];
        gbase[i] = h ? atomicAdd(&bcur[i], h) : 0;
    }

    // place packed pairs into LDS, sorted by bucket
#pragma unroll
    for (int k = 0; k < 16; ++k) {
        if (eb[k] >= 0) {
            int b = eb[k];
            int idx = atomicAdd(&lcur[b], 1);
            spairs[idx] = ((uint32_t)esv[k] << 10) | (uint32_t)(edv[k] - lnlo[b]);
            sbkt[idx]   = (uint16_t)b;
        }
    }
    __syncthreads();

    // coalesced copy-out
    for (int i = t; i < ecnt; i += 256) {
        int b = sbkt[i];
        int pos = gbase[b] + (i - lofs[b]);
        if (pos < BCAP)
            pairs[(size_t)b * BCAP + pos] = spairs[i];
    }
}

// ---------- per-bucket CSR build; pairs staged in LDS, single global read ----------
__global__ void __launch_bounds__(256) k_csr2(
        const uint32_t* __restrict__ pairs, const int* __restrict__ bcur,
        int2* __restrict__ meta, float* __restrict__ dinv,
        int* __restrict__ srcs, int N) {
    __shared__ uint32_t sp[BCAP];          // 16 KB bucket staging
    __shared__ int lcnt[256];
    __shared__ int loff[256];
    __shared__ int lcur[256];
    int b = blockIdx.x, t = threadIdx.x;
    int base = b * BCAP;
    int ec = bcur[b]; if (ec > BCAP) ec = BCAP;
    int nlo = bucket_lo(b, N);
    int nhi = bucket_lo(b + 1, N); if (nhi > N) nhi = N;
    int nn = nhi - nlo;                    // <= 196
    lcnt[t] = 0;
    __syncthreads();
    int ec4 = (ec + 3) >> 2;
    for (int i = t; i < ec4; i += 256) {
        uint4 v = *(const uint4*)(pairs + base + i * 4);
        *(uint4*)&sp[i * 4] = v;
        int lim = ec - i * 4;
        if (lim > 0) atomicAdd(&lcnt[v.x & 1023u], 1);
        if (lim > 1) atomicAdd(&lcnt[v.y & 1023u], 1);
        if (lim > 2) atomicAdd(&lcnt[v.z & 1023u], 1);
        if (lim > 3) atomicAdd(&lcnt[v.w & 1023u], 1);
    }
    __syncthreads();
    int v = lcnt[t];
    int pv = (v + 3) & ~3;                 // pad run to multiple of 4
    loff[t] = pv;
    __syncthreads();
    for (int o = 1; o < 256; o <<= 1) {
        int a = (t >= o) ? loff[t - o] : 0;
        __syncthreads();
        loff[t] += a;
        __syncthreads();
    }
    if (t < nn) {
        int gs = base + (loff[t] - pv);    // exclusive, 4-aligned
        meta[nlo + t] = make_int2(gs, v);
        dinv[nlo + t] = rsqrtf((float)(v + 1));
        lcur[t]       = gs;
    }
    __syncthreads();
    for (int e = t; e < ec; e += 256) {
        uint32_t p = sp[e];
        int pos = atomicAdd(&lcur[p & 1023u], 1);
        srcs[pos] = (int)(p >> 10);
    }
}

// ---------- layer 1 transform via MFMA: g1 = half(dinv * (x @ W1)) ----------
// 64 nodes/block, 4 waves, one 16-node m-tile per wave.
// Compensated fp16 split: x@W ~= xh@Wh + xl@Wh + xh@Wl (err ~2^-22).
// A and B packed with the SAME k-map (k = ks*32 + kg*8 + q) -> correct for any
// internal lane->k permutation since 16x16 A/B layouts are symmetric.
__global__ void __launch_bounds__(256) k_transform1(
        const float* __restrict__ x, const float* __restrict__ W1,
        const float* __restrict__ dinv, __half* __restrict__ g1, int n) {
    __shared__ float sX[T1N * 132];       // padded rows (132 ≡ 4 mod 32 banks)
    __shared__ float sW[128 * 17 + 4];    // padded rows
    int t = threadIdx.x;
    int node0 = blockIdx.x * T1N;
    for (int i = t; i < F_IN * HID; i += 256)
        sW[(i >> 4) * 17 + (i & 15)] = W1[i];
    {
        const float4* xg = (const float4*)(x + (size_t)node0 * F_IN);
        int nrem = n - node0;
#pragma unroll
        for (int j = 0; j < 8; ++j) {
            int idx = t + j * 256;
            int r = idx >> 5, c4 = idx & 31;
            float4 v = make_float4(0.f, 0.f, 0.f, 0.f);
            if (r < nrem) v = xg[idx];
            *(float4*)&sX[r * 132 + c4 * 4] = v;
        }
    }
    __syncthreads();
    int lane = t & 63, wave = t >> 6;
    int mcol = lane & 15, kg = lane >> 4;
    f32x4 acc = {0.f, 0.f, 0.f, 0.f};
#pragma unroll
    for (int ks = 0; ks < 4; ++ks) {
        int k0 = ks * 32 + kg * 8;
        const float* xp = &sX[(wave * 16 + mcol) * 132 + k0];
        float4 v0 = *(const float4*)xp;
        float4 v1 = *(const float4*)(xp + 4);
        float va[8] = {v0.x, v0.y, v0.z, v0.w, v1.x, v1.y, v1.z, v1.w};
        f16x8 ah, al;
#pragma unroll
        for (int q = 0; q < 8; ++q) {
            f16 h = (f16)va[q];
            ah[q] = h;
            al[q] = (f16)(va[q] - (float)h);
        }
        const float* wp = &sW[k0 * 17 + mcol];
        f16x8 bh, bl;
#pragma unroll
        for (int q = 0; q < 8; ++q) {
            float wv = wp[q * 17];
            f16 h = (f16)wv;
            bh[q] = h;
            bl[q] = (f16)(wv - (float)h);
        }
        acc = __builtin_amdgcn_mfma_f32_16x16x32_f16(ah, bh, acc, 0, 0, 0);
        acc = __builtin_amdgcn_mfma_f32_16x16x32_f16(al, bh, acc, 0, 0, 0);
        acc = __builtin_amdgcn_mfma_f32_16x16x32_f16(ah, bl, acc, 0, 0, 0);
    }
    // C/D: col = lane&15 (feature), row = (lane>>4)*4 + r (node)  [HW-verified map]
#pragma unroll
    for (int r = 0; r < 4; ++r) {
        int node = node0 + wave * 16 + kg * 4 + r;
        if (node < n) {
            float di = dinv[node];
            g1[(size_t)node * HID + mcol] = __float2half(di * acc[r]);
        }
    }
}

__device__ __forceinline__ void add_h8(float* __restrict__ acc, const __half* __restrict__ ptr) {
    uint4 u = *(const uint4*)ptr;
    const __half2* h = (const __half2*)&u;
#pragma unroll
    for (int q = 0; q < 4; ++q) {
        float2 f = __half22float2(h[q]);
        acc[2 * q]     += f.x;
        acc[2 * q + 1] += f.y;
    }
}

// accumulate self + neighbors into acc[8] for (node, half p)
__device__ __forceinline__ void gather_acc(
        float* __restrict__ acc, int node, int p,
        const __half* __restrict__ g, const int* __restrict__ srcs,
        int rs, int deg) {
    {
        uint4 u = *(const uint4*)(g + (size_t)node * HID + p * 8);
        const __half2* h = (const __half2*)&u;
#pragma unroll
        for (int q = 0; q < 4; ++q) {
            float2 f = __half22float2(h[q]);
            acc[2 * q] = f.x; acc[2 * q + 1] = f.y;
        }
    }
    int j = 0;
    for (; j + 8 <= deg; j += 8) {
        int4 ia = *(const int4*)(srcs + rs + j);
        int4 ib = *(const int4*)(srcs + rs + j + 4);
        add_h8(acc, g + (size_t)ia.x * HID + p * 8);
        add_h8(acc, g + (size_t)ia.y * HID + p * 8);
        add_h8(acc, g + (size_t)ia.z * HID + p * 8);
        add_h8(acc, g + (size_t)ia.w * HID + p * 8);
        add_h8(acc, g + (size_t)ib.x * HID + p * 8);
        add_h8(acc, g + (size_t)ib.y * HID + p * 8);
        add_h8(acc, g + (size_t)ib.z * HID + p * 8);
        add_h8(acc, g + (size_t)ib.w * HID + p * 8);
    }
    if (j + 4 <= deg) {
        int4 ia = *(const int4*)(srcs + rs + j);
        add_h8(acc, g + (size_t)ia.x * HID + p * 8);
        add_h8(acc, g + (size_t)ia.y * HID + p * 8);
        add_h8(acc, g + (size_t)ia.z * HID + p * 8);
        add_h8(acc, g + (size_t)ia.w * HID + p * 8);
        j += 4;
    }
    for (; j < deg; ++j)
        add_h8(acc, g + (size_t)srcs[rs + j] * HID + p * 8);
}

// ---------- layer-1 gather: 2 threads/node, 16B loads, relu epilogue ----------
__global__ void __launch_bounds__(256) k_gather1(
        const __half* __restrict__ g, const int* __restrict__ srcs,
        const int2* __restrict__ meta, const float* __restrict__ dinv,
        const float* __restrict__ b1, __half* __restrict__ outb, int n) {
    int tt = blockIdx.x * 256 + threadIdx.x;
    int node = tt >> 1;
    int p = tt & 1;
    if (node >= n) return;
    int2 m = meta[node];
    float acc[8];
    gather_acc(acc, node, p, g, srcs, m.x, m.y);
    float di = dinv[node];
#pragma unroll
    for (int i = 0; i < 8; ++i)
        acc[i] = di * fmaxf(di * acc[i] + b1[p * 8 + i], 0.0f);
    uint4 o;
    __half2* oh = (__half2*)&o;
#pragma unroll
    for (int q = 0; q < 4; ++q)
        oh[q] = __floats2half2_rn(acc[2 * q], acc[2 * q + 1]);
    *(uint4*)(outb + (size_t)node * HID + p * 8) = o;
}

// ---------- fused layer-2 gather + MFMA transform2 ----------
// Phase A: gather 128 nodes into LDS (fp16, padded stride AGP).
// Phase B: out = relu(dinv*(agg @ W2) + b2) via 16x16x16 f16 MFMA,
//          W2 compensated-split (agg is exact fp16, so 2 terms suffice).
__global__ void __launch_bounds__(256) k_gather_t2(
        const __half* __restrict__ g, const int* __restrict__ srcs,
        const int2* __restrict__ meta, const float* __restrict__ dinv,
        const float* __restrict__ W2, const float* __restrict__ b2,
        float* __restrict__ out, int n) {
    __shared__ __half sAgg[GT2_NODES * AGP];   // 6 KB
    __shared__ float  sdv[GT2_NODES];
    int t = threadIdx.x;
    int node0 = blockIdx.x * GT2_NODES;

    {   // phase A
        int nl = t >> 1, p = t & 1;
        int node = node0 + nl;
        if (node < n) {
            if (p == 0) sdv[nl] = dinv[node];
            int2 m = meta[node];
            float acc[8];
            gather_acc(acc, node, p, g, srcs, m.x, m.y);
            uint4 o;
            __half2* oh = (__half2*)&o;
#pragma unroll
            for (int q = 0; q < 4; ++q)
                oh[q] = __floats2half2_rn(acc[2 * q], acc[2 * q + 1]);
            *(uint4*)&sAgg[nl * AGP + p * 8] = o;
        }
    }
    __syncthreads();

    // phase B
    int lane = t & 63, wave = t >> 6;
    int fcol = lane & 15, kg = lane >> 4;
    int k0 = kg * 4;
    f16x4 bh[8], bl[8];
    float b2v[8];
#pragma unroll
    for (int nt = 0; nt < 8; ++nt) {
        b2v[nt] = b2[nt * 16 + fcol];
#pragma unroll
        for (int j = 0; j < 4; ++j) {
            float wv = W2[(k0 + j) * F_OUT + nt * 16 + fcol];
            f16 h = (f16)wv;
            bh[nt][j] = h;
            bl[nt][j] = (f16)(wv - (float)h);
        }
    }
    const f16* sA = (const f16*)sAgg;
    f16x4 aA = *(const f16x4*)&sA[(wave * 32 + fcol) * AGP + k0];
    f16x4 aB = *(const f16x4*)&sA[(wave * 32 + 16 + fcol) * AGP + k0];
    f32x4 zero = {0.f, 0.f, 0.f, 0.f};
    f32x4 acc[2][8];
#pragma unroll
    for (int mt = 0; mt < 2; ++mt)
#pragma unroll
        for (int nt = 0; nt < 8; ++nt)
            acc[mt][nt] = zero;
#pragma unroll
    for (int nt = 0; nt < 8; ++nt) {
        acc[0][nt] = __builtin_amdgcn_mfma_f32_16x16x16f16(aA, bh[nt], acc[0][nt], 0, 0, 0);
        acc[0][nt] = __builtin_amdgcn_mfma_f32_16x16x16f16(aA, bl[nt], acc[0][nt], 0, 0, 0);
        acc[1][nt] = __builtin_amdgcn_mfma_f32_16x16x16f16(aB, bh[nt], acc[1][nt], 0, 0, 0);
        acc[1][nt] = __builtin_amdgcn_mfma_f32_16x16x16f16(aB, bl[nt], acc[1][nt], 0, 0, 0);
    }
    // C/D: col = lane&15 (out-feature within n-tile), row = kg*4 + r (node)
#pragma unroll
    for (int mt = 0; mt < 2; ++mt) {
#pragma unroll
        for (int r = 0; r < 4; ++r) {
            int ln = wave * 32 + mt * 16 + kg * 4 + r;
            int node = node0 + ln;
            if (node < n) {
                float dv = sdv[ln];
#pragma unroll
                for (int nt = 0; nt < 8; ++nt)
                    out[(size_t)node * F_OUT + nt * 16 + fcol] =
                        fmaxf(dv * acc[mt][nt][r] + b2v[nt], 0.f);
            }
        }
    }
}

extern "C" void kernel_launch(void* const* d_in, const int* in_sizes, int n_in,
                              void* d_out, int out_size, void* d_ws, size_t ws_size,
                              hipStream_t stream) {
    const float* x  = (const float*)d_in[0];
    const int*   ei = (const int*)d_in[1];
    const float* W1 = (const float*)d_in[2];
    const float* b1 = (const float*)d_in[3];
    const float* W2 = (const float*)d_in[4];
    const float* b2 = (const float*)d_in[5];
    float* out = (float*)d_out;

    const int N = in_sizes[0] / F_IN;
    const int E = in_sizes[1] / 2;

    // workspace layout (all disjoint):
    float* dinv      = (float*)d_ws;                       // N
    int2*  meta      = (int2*)(dinv + N);                  // N int2 (rs,deg)
    int*   bcur      = (int*)(meta + N);                   // NBK
    int*   srcs      = bcur + NBK;                         // NBK*BCAP
    uint32_t* pairs  = (uint32_t*)(srcs + (size_t)NBK * BCAP);  // NBK*BCAP
    __half* bufA     = (__half*)(pairs + (size_t)NBK * BCAP);   // N*HID halves
    __half* bufB     = bufA + (size_t)N * HID;                  // N*HID halves

    hipMemsetAsync(bcur, 0, NBK * sizeof(int), stream);
    k_partf<<<NBLK, 256, 0, stream>>>(ei, bcur, pairs, E, N);
    k_csr2 <<<NBK, 256, 0, stream>>>(pairs, bcur, meta, dinv, srcs, N);
    k_transform1<<<(N + T1N - 1) / T1N, 256, 0, stream>>>(x, W1, dinv, bufA, N);
    k_gather1<<<((size_t)N * 2 + 255) / 256, 256, 0, stream>>>(
        bufA, srcs, meta, dinv, b1, bufB, N);
    k_gather_t2<<<(N + GT2_NODES - 1) / GT2_NODES, 256, 0, stream>>>(
        bufB, srcs, meta, dinv, W2, b2, out, N);
}